// Round 17
// baseline (199.478 us; speedup 1.0000x reference)
//
#include <hip/hip_runtime.h>
#include <hip/hip_bf16.h>
#include <math.h>

#define B 128
#define C 2048
#define N 196
#define K 112
#define KB 113
#define MROWS 128
#define XWROW 113
#define NCLS 200
#define CKC (C * K)
#define NSPL 4             // K split 4-way
#define ITERS 16           // 64 / NSPL
#define MAIN_BLKS 512      // B * NSPL
#define PQ_BLKS 700        // 22400 wids / 32
#define XSTEP 25088        // 32 k-rows * 196 * 4B
#define IMGB (C * N * 4)

#define OUT1_OFF 2834944
#define OUT2_OFF 2849280

typedef __attribute__((ext_vector_type(8))) short bf16x8;
typedef __attribute__((ext_vector_type(4))) float f32x4;

__device__ inline unsigned cvtpk(float a, float b) {
    union { __hip_bfloat162 h; unsigned u; } c;
    c.h.x = __float2bfloat16(a);
    c.h.y = __float2bfloat16(b);
    return c.u;
}
__device__ inline const float* row_src(int row, const float* concepts,
                                       const float* background, const float* wcfc) {
    if (row < K) return concepts + (size_t)row * C;
    if (row == K) return background;
    if (row == XWROW) return wcfc;
    return nullptr;
}
__device__ __forceinline__ void gl16(const void* g, void* l) {
    __builtin_amdgcn_global_load_lds(
        (const __attribute__((address_space(1))) unsigned*)g,
        (__attribute__((address_space(3))) unsigned*)l, 16, 0, 0);
}
__device__ __forceinline__ void gl4(const void* g, void* l) {
    __builtin_amdgcn_global_load_lds(
        (const __attribute__((address_space(1))) unsigned*)g,
        (__attribute__((address_space(3))) unsigned*)l, 4, 0, 0);
}

// ---------------------------------------------------------------------------
__global__ __launch_bounds__(256)
void asq_kernel(const float* __restrict__ concepts, const float* __restrict__ background,
                const float* __restrict__ wcfc, float* __restrict__ asq) {
    const int row = blockIdx.x;
    const int tid = threadIdx.x;
    const float* src = row_src(row, concepts, background, wcfc);
    float local = 0.f;
    if (src) for (int i = tid; i < C; i += 256) { float v = src[i]; local += v * v; }
    for (int off = 32; off; off >>= 1) local += __shfl_down(local, off);
    __shared__ float red[4];
    if ((tid & 63) == 0) red[tid >> 6] = local;
    __syncthreads();
    if (tid == 0) asq[row] = red[0] + red[1] + red[2] + red[3];
}

// ---------------------------------------------------------------------------
// pack: Afrag[kwg 0..63][f 0..7][lane][8 bf16]
// ---------------------------------------------------------------------------
__global__ __launch_bounds__(64)
void pack_kernel(const float* __restrict__ concepts, const float* __restrict__ background,
                 const float* __restrict__ wcfc, unsigned short* __restrict__ Afrag) {
    const int f = blockIdx.x;
    const int kwg = blockIdx.y;
    const int l = threadIdx.x;
    const int row = 16 * f + (l & 15);
    const int kb = 32 * kwg + 8 * (l >> 4);
    const float* src = row_src(row, concepts, background, wcfc);
    unsigned o[4] = {0u, 0u, 0u, 0u};
    if (src) {
        const float4 f0 = *reinterpret_cast<const float4*>(src + kb);
        const float4 f1 = *reinterpret_cast<const float4*>(src + kb + 4);
        o[0] = cvtpk(f0.x, f0.y); o[1] = cvtpk(f0.z, f0.w);
        o[2] = cvtpk(f1.x, f1.y); o[3] = cvtpk(f1.z, f1.w);
    }
    *reinterpret_cast<uint4*>(Afrag + (((size_t)kwg * 8 + f) * 64 + l) * 8) =
        make_uint4(o[0], o[1], o[2], o[3]);
}

// ---------------------------------------------------------------------------
// fused_kernel, 512 thr (8 waves):
//  blk < 512: (image b = blk>>2, K-quarter h = blk&3). 16-iter chain of the
//    R16 loop; partial dots atomically accumulated into out0 (f32 atomicAdd),
//    row-113 partials into xw_ws, column-sumsq partials into xsq_ws.
//  blk >= 512: pq body, 32 wids per block.
// ---------------------------------------------------------------------------
__global__ __launch_bounds__(512)
void fused_kernel(const float* __restrict__ x,
                  const unsigned short* __restrict__ Afrag,
                  float* __restrict__ out0,
                  float* __restrict__ xsq_ws, float* __restrict__ xw_ws,
                  const float* __restrict__ wlfc,
                  const float* __restrict__ concepts,
                  const float* __restrict__ modulation,
                  float* __restrict__ Rm, float* __restrict__ Qs) {
    __shared__ __align__(16) char smem[58624];   // Xf 25600 | Ab 16384 | XT 16640
    const int tid = threadIdx.x;
    const int lane = tid & 63;
    const int w = tid >> 6;
    const int blkid = blockIdx.x;

    if (blkid < MAIN_BLKS) {
        const int b = blkid >> 2;
        const int h = blkid & 3;
        float* Xf = (float*)smem;                              // 25600B
        char* Ab0 = smem + 25600;                              // 2 x 8192
        unsigned short* XT = (unsigned short*)(smem + 41984);  // [208][40] u16

        const int lo = lane & 15, hi = lane >> 4;
        const char* xim = (const char*)x + (size_t)b * IMGB;
        const char* Ag = (const char*)Afrag;

        const bool act = tid < 416;
        const int h2 = (act && tid >= 208) ? 1 : 0;
        const int cc = act ? (tid - 208 * h2) : 0;

        f32x4 acc[13];
#pragma unroll
        for (int ct = 0; ct < 13; ++ct) acc[ct] = (f32x4){0.f, 0.f, 0.f, 0.f};
        float xs = 0.f;

#define ISSUE_X(JJ) do {                                                        \
        const char* sx_ = xim + (size_t)(JJ) * XSTEP;                           \
        gl16(sx_ + (3 * w + 0) * 1024 + lane * 16, smem + (3 * w + 0) * 1024);  \
        gl16(sx_ + (3 * w + 1) * 1024 + lane * 16, smem + (3 * w + 1) * 1024);  \
        gl16(sx_ + (3 * w + 2) * 1024 + lane * 16, smem + (3 * w + 2) * 1024);  \
        if (w < 2) gl4(sx_ + 24576 + w * 256 + lane * 4,                        \
                       smem + 24576 + w * 256);                                 \
    } while (0)

#define ISSUE_A(JJ) do {                                                        \
        gl16(Ag + (size_t)(JJ) * 8192 + w * 1024 + lane * 16,                   \
             Ab0 + ((JJ) & 1) * 8192 + w * 1024);                               \
    } while (0)

#define VM0() do {                                                              \
        asm volatile("s_waitcnt vmcnt(0)" ::: "memory");                        \
        __builtin_amdgcn_sched_barrier(0);                                      \
    } while (0)

#define LBAR() do {                                                             \
        asm volatile("s_waitcnt lgkmcnt(0)" ::: "memory");                      \
        __builtin_amdgcn_s_barrier();                                           \
        __builtin_amdgcn_sched_barrier(0);                                      \
    } while (0)

#define CONVERT() do {                                                          \
        if (act) {                                                              \
            const float* xp_ = Xf + (16 * h2) * 196 + cc;                       \
            float v_[16];                                                       \
            _Pragma("unroll")                                                   \
            for (int q_ = 0; q_ < 16; ++q_) v_[q_] = xp_[q_ * 196];             \
            _Pragma("unroll")                                                   \
            for (int q_ = 0; q_ < 16; ++q_) xs += v_[q_] * v_[q_];              \
            unsigned u_[8];                                                     \
            _Pragma("unroll")                                                   \
            for (int p_ = 0; p_ < 8; ++p_)                                      \
                u_[p_] = cvtpk(v_[2 * p_], v_[2 * p_ + 1]);                     \
            unsigned short* xt_ = XT + cc * 40 + h2 * 16;                       \
            *reinterpret_cast<uint4*>(xt_) = make_uint4(u_[0], u_[1], u_[2], u_[3]); \
            *reinterpret_cast<uint4*>(xt_ + 8) = make_uint4(u_[4], u_[5], u_[6], u_[7]); \
        }                                                                       \
    } while (0)

#define MFMA_STEP(JJ) do {                                                      \
        const char* Ab_ = Ab0 + ((JJ) & 1) * 8192;                              \
        const bf16x8 afr_ = *reinterpret_cast<const bf16x8*>(                   \
            Ab_ + ((w * 64 + lane) << 4));                                      \
        _Pragma("unroll")                                                       \
        for (int ct_ = 0; ct_ < 13; ++ct_) {                                    \
            const bf16x8 bfr_ = *reinterpret_cast<const bf16x8*>(               \
                (const char*)XT + (ct_ * 16 + lo) * 80 + hi * 16);              \
            acc[ct_] = __builtin_amdgcn_mfma_f32_16x16x32_bf16(                 \
                afr_, bfr_, acc[ct_], 0, 0, 0);                                 \
        }                                                                       \
    } while (0)

        const int j0 = h * ITERS;
        ISSUE_X(j0); ISSUE_A(j0);
#pragma unroll 1
        for (int jj = 0; jj < ITERS - 1; ++jj) {
            const int j = j0 + jj;
            VM0(); LBAR();
            CONVERT();
            LBAR();
            ISSUE_X(j + 1);
            MFMA_STEP(j);
            ISSUE_A(j + 1);
        }
        VM0(); LBAR(); CONVERT(); LBAR(); MFMA_STEP(j0 + ITERS - 1);

        // ---- epilogue: atomically accumulate partials ----
        if (act) atomicAdd(&xsq_ws[(size_t)b * 208 + cc], xs);
        const bool v4 = (w < 7);
        float* od = out0 + (size_t)b * KB * N;
#pragma unroll
        for (int ct = 0; ct < 13; ++ct) {
            const int c = ct * 16 + lo;
            if (c < N) {
#pragma unroll
                for (int rr = 0; rr < 4; ++rr) {
                    const int r = 16 * w + 4 * hi + rr;
                    if (v4 || (hi == 0 && rr == 0))
                        atomicAdd(&od[(size_t)r * N + c], acc[ct][rr]);
                }
                if (w == 7 && hi == 0)
                    atomicAdd(&xw_ws[(size_t)b * 208 + c], acc[ct][1]);  // row 113
            }
        }
    } else {
        // ---------------- pq body: 32 wids per block (4 per wave) -----------
        const int wb = (blkid - MAIN_BLKS) * 32 + w * 4;
#pragma unroll
        for (int q = 0; q < 4; ++q) {
            const int wid = wb + q;
            const int o = wid / K;
            const int k = wid % K;
            const float4* wp = reinterpret_cast<const float4*>(wlfc + (size_t)o * CKC + (size_t)k * C);
            const float4* cp = reinterpret_cast<const float4*>(concepts + (size_t)k * C);
            const float4* mp = reinterpret_cast<const float4*>(modulation);
            float s1 = 0.f, s2 = 0.f;
#pragma unroll
            for (int it = 0; it < 8; ++it) {
                const int idx = it * 64 + lane;
                const float4 w4 = wp[idx];
                const float4 c4 = cp[idx];
                const float4 m4 = mp[idx];
                s1 += w4.x * c4.x + w4.y * c4.y + w4.z * c4.z + w4.w * c4.w;
                s2 += w4.x * m4.x + w4.y * m4.y + w4.z * m4.z + w4.w * m4.w;
            }
            for (int off = 32; off; off >>= 1) {
                s1 += __shfl_down(s1, off);
                s2 += __shfl_down(s2, off);
            }
            if (lane == 0) { Rm[wid] = s1 - s2; Qs[wid] = s2; }
        }
    }
}

// ---------------------------------------------------------------------------
// softmax_kernel: per image, read summed dots from out0, apply dist+softmax,
// rewrite out0 in place, emit lpart. Same thread/value layout as R16 epilogue.
// ---------------------------------------------------------------------------
__global__ __launch_bounds__(512)
void softmax_kernel(float* __restrict__ out0,
                    const float* __restrict__ xsq_ws, const float* __restrict__ xw_ws,
                    const float* __restrict__ asq_g,
                    float* __restrict__ lpart) {
    __shared__ float pmw[8 * 208];
    __shared__ float xsqL[208];
    __shared__ float xwL[208];
    const int b = blockIdx.x;
    const int tid = threadIdx.x;
    const int lane = tid & 63;
    const int w = tid >> 6;
    const int lo = lane & 15, hi = lane >> 4;

    if (tid < 208) {
        xsqL[tid] = xsq_ws[(size_t)b * 208 + tid];
        xwL[tid] = xw_ws[(size_t)b * 208 + tid];
    }
    __syncthreads();

    const bool v4 = (w < 7);
    float* od = out0 + (size_t)b * KB * N;

    f32x4 acc[13];
    float aq[4];
#pragma unroll
    for (int rr = 0; rr < 4; ++rr) aq[rr] = asq_g[16 * w + 4 * hi + rr];

#pragma unroll
    for (int ct = 0; ct < 13; ++ct) {
        const int c = ct * 16 + lo;
        const bool cv = c < N;
#pragma unroll
        for (int rr = 0; rr < 4; ++rr) {
            const int r = 16 * w + 4 * hi + rr;
            const bool valid = v4 || (hi == 0 && rr == 0);
            acc[ct][rr] = (valid && cv) ? od[(size_t)r * N + c] : 0.f;
        }
    }

    float mct[13];
#pragma unroll
    for (int ct = 0; ct < 13; ++ct) {
        const int c = ct * 16 + lo;
#pragma unroll
        for (int rr = 0; rr < 4; ++rr) {
            const float d2 = aq[rr] + xsqL[c] - 2.f * acc[ct][rr];
            acc[ct][rr] = -sqrtf(fmaxf(d2, 0.f));
        }
        float mv = -3.4e38f;
        if (v4) mv = fmaxf(fmaxf(acc[ct][0], acc[ct][1]),
                           fmaxf(acc[ct][2], acc[ct][3]));
        else if (hi == 0) mv = acc[ct][0];
        mv = fmaxf(mv, __shfl_xor(mv, 16));
        mv = fmaxf(mv, __shfl_xor(mv, 32));
        mct[ct] = mv;
    }
    if (hi == 0) {
#pragma unroll
        for (int ct = 0; ct < 13; ++ct) pmw[w * 208 + ct * 16 + lo] = mct[ct];
    }
    __syncthreads();
    float Mct[13];
#pragma unroll
    for (int ct = 0; ct < 13; ++ct) {
        float mm = -3.4e38f;
#pragma unroll
        for (int ww = 0; ww < 8; ++ww)
            mm = fmaxf(mm, pmw[ww * 208 + ct * 16 + lo]);
        Mct[ct] = mm;
    }
    __syncthreads();
    float sct[13];
#pragma unroll
    for (int ct = 0; ct < 13; ++ct) {
        float ss = 0.f;
#pragma unroll
        for (int rr = 0; rr < 4; ++rr) {
            const bool valid = v4 || (hi == 0 && rr == 0);
            const float e = valid ? __expf(acc[ct][rr] - Mct[ct]) : 0.f;
            acc[ct][rr] = e;
            ss += e;
        }
        ss += __shfl_xor(ss, 16);
        ss += __shfl_xor(ss, 32);
        sct[ct] = ss;
    }
    if (hi == 0) {
#pragma unroll
        for (int ct = 0; ct < 13; ++ct) pmw[w * 208 + ct * 16 + lo] = sct[ct];
    }
    __syncthreads();
    float inv[13];
#pragma unroll
    for (int ct = 0; ct < 13; ++ct) {
        float SS = 0.f;
#pragma unroll
        for (int ww = 0; ww < 8; ++ww) SS += pmw[ww * 208 + ct * 16 + lo];
        inv[ct] = 1.f / SS;
    }

#pragma unroll
    for (int ct = 0; ct < 13; ++ct) {
        const int c = ct * 16 + lo;
        const bool cv = c < N;
#pragma unroll
        for (int rr = 0; rr < 4; ++rr) {
            const int r = 16 * w + 4 * hi + rr;
            const bool valid = v4 || (hi == 0 && rr == 0);
            if (valid && cv) od[(size_t)r * N + c] = acc[ct][rr] * inv[ct];
        }
    }
    if (v4) {
#pragma unroll
        for (int rr = 0; rr < 4; ++rr) {
            float pv = 0.f;
#pragma unroll
            for (int ct = 0; ct < 13; ++ct) {
                const int c = ct * 16 + lo;
                const float term = acc[ct][rr] * inv[ct] * xwL[c];
                pv += (c < N) ? term : 0.f;
            }
            pv += __shfl_xor(pv, 1);
            pv += __shfl_xor(pv, 2);
            pv += __shfl_xor(pv, 4);
            pv += __shfl_xor(pv, 8);
            if (lo == 0) lpart[(size_t)b * K + 16 * w + 4 * hi + rr] = pv;
        }
    }
}

// ---------------------------------------------------------------------------
__global__ __launch_bounds__(256)
void final_kernel(const float* __restrict__ lpart, const float* __restrict__ bcfc,
                  const float* __restrict__ Rm, const float* __restrict__ Qs,
                  const float* __restrict__ blfc,
                  float* __restrict__ out1, float* __restrict__ out2) {
    const int b = blockIdx.x;
    const int tid = threadIdx.x;
    __shared__ float g_s[K];
    if (tid < K) {
        const float v = lpart[(size_t)b * K + tid] + bcfc[0];
        const float g = 1.f / (1.f + __expf(-v));
        out1[b * K + tid] = g;
        g_s[tid] = g;
    }
    __syncthreads();
    if (tid < NCLS) {
        float acc = blfc[tid];
        const float* rp = Rm + (size_t)tid * K;
        const float* qp = Qs + (size_t)tid * K;
        for (int k = 0; k < K; ++k) acc = fmaf(g_s[k], rp[k], acc) + qp[k];
        out2[b * NCLS + tid] = acc;
    }
}

extern "C" void kernel_launch(void* const* d_in, const int* in_sizes, int n_in,
                              void* d_out, int out_size, void* d_ws, size_t ws_size,
                              hipStream_t stream) {
    const float* x          = (const float*)d_in[0];
    const float* concepts   = (const float*)d_in[1];
    const float* modulation = (const float*)d_in[2];
    const float* background = (const float*)d_in[3];
    const float* wcfc       = (const float*)d_in[4];
    const float* bcfc       = (const float*)d_in[5];
    const float* wlfc       = (const float*)d_in[6];
    const float* blfc       = (const float*)d_in[7];

    float* out  = (float*)d_out;
    float* out0 = out;
    float* out1 = out + OUT1_OFF;
    float* out2 = out + OUT2_OFF;

    float* ws     = (float*)d_ws;
    float* asq    = ws;                               // 128
    float* lpart  = asq + MROWS;                      // B*K
    float* Rm     = lpart + (size_t)B * K;            // 22400
    float* Qs     = Rm + NCLS * K;                    // 22400
    float* xsq_ws = Qs + NCLS * K;                    // B*208
    float* xw_ws  = xsq_ws + (size_t)B * 208;         // B*208
    unsigned short* Afrag = (unsigned short*)(xw_ws + (size_t)B * 208);  // 512KB

    // zero accumulation targets (graph-safe async memsets)
    hipMemsetAsync(out0, 0, (size_t)OUT1_OFF * sizeof(float), stream);
    hipMemsetAsync(xsq_ws, 0, (size_t)2 * B * 208 * sizeof(float), stream);

    asq_kernel<<<MROWS, 256, 0, stream>>>(concepts, background, wcfc, asq);
    pack_kernel<<<dim3(8, 64), 64, 0, stream>>>(concepts, background, wcfc, Afrag);
    fused_kernel<<<MAIN_BLKS + PQ_BLKS, 512, 0, stream>>>(
        x, Afrag, out0, xsq_ws, xw_ws, wlfc, concepts, modulation, Rm, Qs);
    softmax_kernel<<<B, 512, 0, stream>>>(out0, xsq_ws, xw_ws, asq, lpart);
    final_kernel<<<B, 256, 0, stream>>>(lpart, bcfc, Rm, Qs, blfc, out1, out2);
}

// Round 18
// 128.933 us; speedup vs baseline: 1.5471x; 1.5471x over previous
//
#include <hip/hip_runtime.h>
#include <hip/hip_bf16.h>
#include <math.h>

#define B 128
#define C 2048
#define N 196
#define K 112
#define KB 113
#define MROWS 128
#define XWROW 113
#define NCLS 200
#define CKC (C * K)
#define MAIN_BLKS 128
#define PQ_BLKS 700        // 22400 wids / 32
#define XSTEP 25088        // 32 k-rows * 196 cols * 4B
#define IMGB (C * N * 4)
#define XFSLOT 25600
#define ABASE 76800        // 3 * XFSLOT
#define XTBASE 109568      // ABASE + 4*8192
#define SMEMSZ 142848      // XTBASE + 2*16640

#define OUT1_OFF 2834944
#define OUT2_OFF 2849280

typedef __attribute__((ext_vector_type(8))) short bf16x8;
typedef __attribute__((ext_vector_type(4))) float f32x4;

__device__ inline unsigned cvtpk(float a, float b) {
    union { __hip_bfloat162 h; unsigned u; } c;
    c.h.x = __float2bfloat16(a);
    c.h.y = __float2bfloat16(b);
    return c.u;
}
__device__ inline const float* row_src(int row, const float* concepts,
                                       const float* background, const float* wcfc) {
    if (row < K) return concepts + (size_t)row * C;
    if (row == K) return background;
    if (row == XWROW) return wcfc;
    return nullptr;
}
__device__ __forceinline__ void gl16(const void* g, void* l) {
    __builtin_amdgcn_global_load_lds(
        (const __attribute__((address_space(1))) unsigned*)g,
        (__attribute__((address_space(3))) unsigned*)l, 16, 0, 0);
}

// ---------------------------------------------------------------------------
__global__ __launch_bounds__(256)
void asq_kernel(const float* __restrict__ concepts, const float* __restrict__ background,
                const float* __restrict__ wcfc, float* __restrict__ asq) {
    const int row = blockIdx.x;
    const int tid = threadIdx.x;
    const float* src = row_src(row, concepts, background, wcfc);
    float local = 0.f;
    if (src) for (int i = tid; i < C; i += 256) { float v = src[i]; local += v * v; }
    for (int off = 32; off; off >>= 1) local += __shfl_down(local, off);
    __shared__ float red[4];
    if ((tid & 63) == 0) red[tid >> 6] = local;
    __syncthreads();
    if (tid == 0) asq[row] = red[0] + red[1] + red[2] + red[3];
}

// ---------------------------------------------------------------------------
// pack: Afrag[kwg 0..63][f 0..7][lane][8 bf16]
// ---------------------------------------------------------------------------
__global__ __launch_bounds__(64)
void pack_kernel(const float* __restrict__ concepts, const float* __restrict__ background,
                 const float* __restrict__ wcfc, unsigned short* __restrict__ Afrag) {
    const int f = blockIdx.x;
    const int kwg = blockIdx.y;
    const int l = threadIdx.x;
    const int row = 16 * f + (l & 15);
    const int kb = 32 * kwg + 8 * (l >> 4);
    const float* src = row_src(row, concepts, background, wcfc);
    unsigned o[4] = {0u, 0u, 0u, 0u};
    if (src) {
        const float4 f0 = *reinterpret_cast<const float4*>(src + kb);
        const float4 f1 = *reinterpret_cast<const float4*>(src + kb + 4);
        o[0] = cvtpk(f0.x, f0.y); o[1] = cvtpk(f0.z, f0.w);
        o[2] = cvtpk(f1.x, f1.y); o[3] = cvtpk(f1.z, f1.w);
    }
    *reinterpret_cast<uint4*>(Afrag + (((size_t)kwg * 8 + f) * 64 + l) * 8) =
        make_uint4(o[0], o[1], o[2], o[3]);
}

// ---------------------------------------------------------------------------
// fused_kernel, 512 thr (8 waves = 4 row-tiles x 2 col-halves):
//  blk < 128: whole-image GEMM dots[128][208] = A @ x_b. Per K-step: DMA x+A
//    (counted vmcnt, 2 stages ahead, Xf x3 / A x4 / XT x2 rings), CONVERT
//    f32->bf16, wave (wr,wc): 2 A-frags x 7(6) B-frags = 13-14 MFMA.
//    ONE lgkm barrier + ONE counted vmcnt per iter (no vm drain).
//  blk >= 128: pq body (w_lfc sweep), 32 wids per block.
// ---------------------------------------------------------------------------
__global__ __launch_bounds__(512)
void fused_kernel(const float* __restrict__ x,
                  const unsigned short* __restrict__ Afrag,
                  const float* __restrict__ asq_g,
                  float* __restrict__ out0,
                  float* __restrict__ lpart,
                  const float* __restrict__ wlfc,
                  const float* __restrict__ concepts,
                  const float* __restrict__ modulation,
                  float* __restrict__ Rm, float* __restrict__ Qs) {
    __shared__ __align__(16) char smem[SMEMSZ];
    const int tid = threadIdx.x;
    const int lane = tid & 63;
    const int w = tid >> 6;
    const int blkid = blockIdx.x;

    if (blkid < MAIN_BLKS) {
        const int b = blkid;
        const int lo = lane & 15, hi = lane >> 4;
        const int wr = w & 3, wc = w >> 2;
        const int nct = 7 - wc;               // 7 col-tiles (wc=0) / 6 (wc=1)

        const char* xim = (const char*)x + (size_t)b * IMGB;
        const char* Ag = (const char*)Afrag;
        unsigned short* XTb = (unsigned short*)(smem + XTBASE);

        const bool act = tid < 416;
        const int h2 = (act && tid >= 208) ? 1 : 0;
        const int cc = act ? (tid - 208 * h2) : 0;

        f32x4 acc[2][7];
#pragma unroll
        for (int rt = 0; rt < 2; ++rt)
#pragma unroll
            for (int ct = 0; ct < 7; ++ct) acc[rt][ct] = (f32x4){0.f, 0.f, 0.f, 0.f};
        float xs = 0.f;

#define ISSUE(JJ) do {                                                          \
        const char* sx_ = xim + (size_t)(JJ) * XSTEP;                           \
        char* xb_ = smem + ((JJ) % 3) * XFSLOT;                                 \
        gl16(sx_ + (3 * w + 0) * 1024 + lane * 16, xb_ + (3 * w + 0) * 1024);   \
        gl16(sx_ + (3 * w + 1) * 1024 + lane * 16, xb_ + (3 * w + 1) * 1024);   \
        gl16(sx_ + (3 * w + 2) * 1024 + lane * 16, xb_ + (3 * w + 2) * 1024);   \
        if (w == 0) gl16(sx_ + 24064 + lane * 16, xb_ + 24064);                 \
        gl16(Ag + (size_t)(JJ) * 8192 + w * 1024 + lane * 16,                   \
             smem + ABASE + ((JJ) % 4) * 8192 + w * 1024);                      \
    } while (0)

#define CONVERT(JJ) do {                                                        \
        if (act) {                                                              \
            const float* xp_ = (const float*)(smem + ((JJ) % 3) * XFSLOT)       \
                               + (16 * h2) * 196 + cc;                          \
            float v_[16];                                                       \
            _Pragma("unroll")                                                   \
            for (int q_ = 0; q_ < 16; ++q_) v_[q_] = xp_[q_ * 196];             \
            _Pragma("unroll")                                                   \
            for (int q_ = 0; q_ < 16; ++q_) xs += v_[q_] * v_[q_];              \
            unsigned u_[8];                                                     \
            _Pragma("unroll")                                                   \
            for (int p_ = 0; p_ < 8; ++p_)                                      \
                u_[p_] = cvtpk(v_[2 * p_], v_[2 * p_ + 1]);                     \
            unsigned short* xt_ = XTb + ((JJ) & 1) * 8320 + cc * 40 + h2 * 16;  \
            *reinterpret_cast<uint4*>(xt_) = make_uint4(u_[0], u_[1], u_[2], u_[3]); \
            *reinterpret_cast<uint4*>(xt_ + 8) = make_uint4(u_[4], u_[5], u_[6], u_[7]); \
        }                                                                       \
    } while (0)

#define MFMA_STEP(JJ) do {                                                      \
        const char* Ab_ = smem + ABASE + ((JJ) % 4) * 8192;                     \
        bf16x8 af0_ = *reinterpret_cast<const bf16x8*>(                         \
            Ab_ + ((2 * wr + 0) * 64 + lane) * 16);                             \
        bf16x8 af1_ = *reinterpret_cast<const bf16x8*>(                         \
            Ab_ + ((2 * wr + 1) * 64 + lane) * 16);                             \
        const char* xt_ = (const char*)XTb + ((JJ) & 1) * 16640;                \
        _Pragma("unroll")                                                       \
        for (int ct_ = 0; ct_ < 7; ++ct_) {                                     \
            if (ct_ < nct) {                                                    \
                const bf16x8 bf_ = *reinterpret_cast<const bf16x8*>(            \
                    xt_ + ((wc * 7 + ct_) * 16 + lo) * 80 + hi * 16);           \
                acc[0][ct_] = __builtin_amdgcn_mfma_f32_16x16x32_bf16(          \
                    af0_, bf_, acc[0][ct_], 0, 0, 0);                           \
                acc[1][ct_] = __builtin_amdgcn_mfma_f32_16x16x32_bf16(          \
                    af1_, bf_, acc[1][ct_], 0, 0, 0);                           \
            }                                                                   \
        }                                                                       \
    } while (0)

        ISSUE(0); ISSUE(1);
#pragma unroll 1
        for (int j = 0; j < 64; ++j) {
            asm volatile("s_waitcnt lgkmcnt(0)" ::: "memory");
            if (j < 63) {
                if (w == 0) asm volatile("s_waitcnt vmcnt(5)" ::: "memory");
                else        asm volatile("s_waitcnt vmcnt(4)" ::: "memory");
            } else {
                asm volatile("s_waitcnt vmcnt(0)" ::: "memory");
            }
            __builtin_amdgcn_s_barrier();
            __builtin_amdgcn_sched_barrier(0);
            if (j < 62) ISSUE(j + 2);
            CONVERT(j);
            if (j > 0) MFMA_STEP(j - 1);
        }
        asm volatile("s_waitcnt lgkmcnt(0)" ::: "memory");
        __builtin_amdgcn_s_barrier();
        __builtin_amdgcn_sched_barrier(0);
        MFMA_STEP(63);

        // ------------------ epilogue ------------------
        float* pmw  = (float*)smem;             // [4][208]
        float* xsqL = (float*)(smem + 3584);    // [2][208]
        float* xwL  = (float*)(smem + 5376);    // [208]
        float* lpw  = (float*)(smem + 6272);    // [2][128]

        __syncthreads();
        if (act) xsqL[h2 * 208 + cc] = xs;
        if (wr == 3 && hi == 0) {
#pragma unroll
            for (int ct = 0; ct < 7; ++ct)
                if (ct < nct) xwL[112 * wc + 16 * ct + lo] = acc[1][ct][1];  // raw row 113
        }
        __syncthreads();

        float xq[7];
#pragma unroll
        for (int ct = 0; ct < 7; ++ct)
            if (ct < nct) {
                const int c = 112 * wc + 16 * ct + lo;
                xq[ct] = xsqL[c] + xsqL[208 + c];
            }
        float aq0[4], aq1[4];
#pragma unroll
        for (int rr = 0; rr < 4; ++rr) {
            aq0[rr] = asq_g[32 * wr + 4 * hi + rr];
            aq1[rr] = asq_g[32 * wr + 16 + 4 * hi + rr];
        }

        float mct[7];
#pragma unroll
        for (int ct = 0; ct < 7; ++ct) {
            if (ct < nct) {
                float mv = -3.4e38f;
#pragma unroll
                for (int rr = 0; rr < 4; ++rr) {
                    const float L0 = -sqrtf(fmaxf(aq0[rr] + xq[ct] - 2.f * acc[0][ct][rr], 0.f));
                    const float L1 = -sqrtf(fmaxf(aq1[rr] + xq[ct] - 2.f * acc[1][ct][rr], 0.f));
                    acc[0][ct][rr] = L0;
                    acc[1][ct][rr] = L1;
                    mv = fmaxf(mv, L0);                       // rt0 rows always < 112
                    const bool valid1 = (wr < 3) || (hi == 0 && rr == 0);
                    if (valid1) mv = fmaxf(mv, L1);
                }
                mv = fmaxf(mv, __shfl_xor(mv, 16));
                mv = fmaxf(mv, __shfl_xor(mv, 32));
                mct[ct] = mv;
            }
        }
        if (hi == 0) {
#pragma unroll
            for (int ct = 0; ct < 7; ++ct)
                if (ct < nct) pmw[wr * 208 + 112 * wc + 16 * ct + lo] = mct[ct];
        }
        __syncthreads();
        float Mct[7];
#pragma unroll
        for (int ct = 0; ct < 7; ++ct)
            if (ct < nct) {
                const int c = 112 * wc + 16 * ct + lo;
                Mct[ct] = fmaxf(fmaxf(pmw[c], pmw[208 + c]),
                                fmaxf(pmw[416 + c], pmw[624 + c]));
            }
        __syncthreads();
#pragma unroll
        for (int ct = 0; ct < 7; ++ct) {
            if (ct < nct) {
                float ss = 0.f;
#pragma unroll
                for (int rr = 0; rr < 4; ++rr) {
                    const float e0 = __expf(acc[0][ct][rr] - Mct[ct]);
                    acc[0][ct][rr] = e0;
                    ss += e0;
                    const bool valid1 = (wr < 3) || (hi == 0 && rr == 0);
                    const float e1 = valid1 ? __expf(acc[1][ct][rr] - Mct[ct]) : 0.f;
                    acc[1][ct][rr] = e1;
                    ss += e1;
                }
                ss += __shfl_xor(ss, 16);
                ss += __shfl_xor(ss, 32);
                if (hi == 0) pmw[wr * 208 + 112 * wc + 16 * ct + lo] = ss;
            }
        }
        __syncthreads();
        float inv[7];
#pragma unroll
        for (int ct = 0; ct < 7; ++ct)
            if (ct < nct) {
                const int c = 112 * wc + 16 * ct + lo;
                inv[ct] = 1.f / (pmw[c] + pmw[208 + c] + pmw[416 + c] + pmw[624 + c]);
            }

        float* od = out0 + (size_t)b * KB * N;
#pragma unroll
        for (int ct = 0; ct < 7; ++ct) {
            if (ct < nct) {
                const int c = 112 * wc + 16 * ct + lo;
                const bool cv = c < N;
#pragma unroll
                for (int rr = 0; rr < 4; ++rr) {
                    const int r0 = 32 * wr + 4 * hi + rr;
                    if (cv) od[(size_t)r0 * N + c] = acc[0][ct][rr] * inv[ct];
                    const bool valid1 = (wr < 3) || (hi == 0 && rr == 0);
                    if (valid1 && cv) od[(size_t)(r0 + 16) * N + c] = acc[1][ct][rr] * inv[ct];
                }
            }
        }
        // lpart partials: rows 0..111
#pragma unroll
        for (int rr = 0; rr < 4; ++rr) {
            float pv0 = 0.f, pv1 = 0.f;
#pragma unroll
            for (int ct = 0; ct < 7; ++ct) {
                if (ct < nct) {
                    const int c = 112 * wc + 16 * ct + lo;
                    const float t0 = acc[0][ct][rr] * inv[ct] * xwL[c];
                    const float t1 = acc[1][ct][rr] * inv[ct] * xwL[c];
                    pv0 += (c < N) ? t0 : 0.f;
                    pv1 += (c < N) ? t1 : 0.f;
                }
            }
            pv0 += __shfl_xor(pv0, 1); pv0 += __shfl_xor(pv0, 2);
            pv0 += __shfl_xor(pv0, 4); pv0 += __shfl_xor(pv0, 8);
            pv1 += __shfl_xor(pv1, 1); pv1 += __shfl_xor(pv1, 2);
            pv1 += __shfl_xor(pv1, 4); pv1 += __shfl_xor(pv1, 8);
            if (lo == 0) {
                lpw[wc * 128 + 32 * wr + 4 * hi + rr] = pv0;
                if (wr < 3) lpw[wc * 128 + 32 * wr + 16 + 4 * hi + rr] = pv1;
            }
        }
        __syncthreads();
        if (tid < K) lpart[(size_t)b * K + tid] = lpw[tid] + lpw[128 + tid];
    } else {
        // ---------------- pq body: 32 wids per block (4 per wave) -----------
        const int wb = (blkid - MAIN_BLKS) * 32 + w * 4;
#pragma unroll
        for (int q = 0; q < 4; ++q) {
            const int wid = wb + q;
            const int o = wid / K;
            const int k = wid % K;
            const float4* wp = reinterpret_cast<const float4*>(wlfc + (size_t)o * CKC + (size_t)k * C);
            const float4* cp = reinterpret_cast<const float4*>(concepts + (size_t)k * C);
            const float4* mp = reinterpret_cast<const float4*>(modulation);
            float s1 = 0.f, s2 = 0.f;
#pragma unroll
            for (int it = 0; it < 8; ++it) {
                const int idx = it * 64 + lane;
                const float4 w4 = wp[idx];
                const float4 c4 = cp[idx];
                const float4 m4 = mp[idx];
                s1 += w4.x * c4.x + w4.y * c4.y + w4.z * c4.z + w4.w * c4.w;
                s2 += w4.x * m4.x + w4.y * m4.y + w4.z * m4.z + w4.w * m4.w;
            }
            for (int off = 32; off; off >>= 1) {
                s1 += __shfl_down(s1, off);
                s2 += __shfl_down(s2, off);
            }
            if (lane == 0) { Rm[wid] = s1 - s2; Qs[wid] = s2; }
        }
    }
}

// ---------------------------------------------------------------------------
__global__ __launch_bounds__(256)
void final_kernel(const float* __restrict__ lpart, const float* __restrict__ bcfc,
                  const float* __restrict__ Rm, const float* __restrict__ Qs,
                  const float* __restrict__ blfc,
                  float* __restrict__ out1, float* __restrict__ out2) {
    const int b = blockIdx.x;
    const int tid = threadIdx.x;
    __shared__ float g_s[K];
    if (tid < K) {
        const float v = lpart[(size_t)b * K + tid] + bcfc[0];
        const float g = 1.f / (1.f + __expf(-v));
        out1[b * K + tid] = g;
        g_s[tid] = g;
    }
    __syncthreads();
    if (tid < NCLS) {
        float acc = blfc[tid];
        const float* rp = Rm + (size_t)tid * K;
        const float* qp = Qs + (size_t)tid * K;
        for (int k = 0; k < K; ++k) acc = fmaf(g_s[k], rp[k], acc) + qp[k];
        out2[b * NCLS + tid] = acc;
    }
}

extern "C" void kernel_launch(void* const* d_in, const int* in_sizes, int n_in,
                              void* d_out, int out_size, void* d_ws, size_t ws_size,
                              hipStream_t stream) {
    const float* x          = (const float*)d_in[0];
    const float* concepts   = (const float*)d_in[1];
    const float* modulation = (const float*)d_in[2];
    const float* background = (const float*)d_in[3];
    const float* wcfc       = (const float*)d_in[4];
    const float* bcfc       = (const float*)d_in[5];
    const float* wlfc       = (const float*)d_in[6];
    const float* blfc       = (const float*)d_in[7];

    float* out  = (float*)d_out;
    float* out0 = out;
    float* out1 = out + OUT1_OFF;
    float* out2 = out + OUT2_OFF;

    float* ws    = (float*)d_ws;
    float* asq   = ws;                               // 128
    float* lpart = asq + MROWS;                      // B*K
    float* Rm    = lpart + (size_t)B * K;            // 22400
    float* Qs    = Rm + NCLS * K;                    // 22400
    unsigned short* Afrag = (unsigned short*)(Qs + NCLS * K);  // 512KB

    asq_kernel<<<MROWS, 256, 0, stream>>>(concepts, background, wcfc, asq);
    pack_kernel<<<dim3(8, 64), 64, 0, stream>>>(concepts, background, wcfc, Afrag);
    fused_kernel<<<MAIN_BLKS + PQ_BLKS, 512, 0, stream>>>(
        x, Afrag, asq, out0, lpart, wlfc, concepts, modulation, Rm, Qs);
    final_kernel<<<B, 256, 0, stream>>>(lpart, bcfc, Rm, Qs, blfc, out1, out2);
}

// Round 19
// 115.373 us; speedup vs baseline: 1.7290x; 1.1175x over previous
//
#include <hip/hip_runtime.h>
#include <hip/hip_bf16.h>
#include <math.h>

#define B 128
#define C 2048
#define N 196
#define K 112
#define KB 113
#define MROWS 128
#define XWROW 113
#define NCLS 200
#define CKC (C * K)
#define MAIN_BLKS 128
#define PQ_BLKS 700        // 22400 wids / 32
#define XSTEP 25088        // 32 k-rows * 196 cols * 4B
#define IMGB (C * N * 4)
#define XFSLOT 25600
#define ABASE 51200        // 2 ring slots x 16384 (each = 2 ksteps x 8KB)
#define XTBASE 83968       // 2 x 16640
#define SMEMSZ 117248

#define OUT1_OFF 2834944
#define OUT2_OFF 2849280

typedef __attribute__((ext_vector_type(8))) short bf16x8;
typedef __attribute__((ext_vector_type(4))) float f32x4;

__device__ inline unsigned cvtpk(float a, float b) {
    union { __hip_bfloat162 h; unsigned u; } c;
    c.h.x = __float2bfloat16(a);
    c.h.y = __float2bfloat16(b);
    return c.u;
}
__device__ inline const float* row_src(int row, const float* concepts,
                                       const float* background, const float* wcfc) {
    if (row < K) return concepts + (size_t)row * C;
    if (row == K) return background;
    if (row == XWROW) return wcfc;
    return nullptr;
}
__device__ __forceinline__ void gl16(const void* g, void* l) {
    __builtin_amdgcn_global_load_lds(
        (const __attribute__((address_space(1))) unsigned*)g,
        (__attribute__((address_space(3))) unsigned*)l, 16, 0, 0);
}

// ---------------------------------------------------------------------------
__global__ __launch_bounds__(256)
void asq_kernel(const float* __restrict__ concepts, const float* __restrict__ background,
                const float* __restrict__ wcfc, float* __restrict__ asq) {
    const int row = blockIdx.x;
    const int tid = threadIdx.x;
    const float* src = row_src(row, concepts, background, wcfc);
    float local = 0.f;
    if (src) for (int i = tid; i < C; i += 256) { float v = src[i]; local += v * v; }
    for (int off = 32; off; off >>= 1) local += __shfl_down(local, off);
    __shared__ float red[4];
    if ((tid & 63) == 0) red[tid >> 6] = local;
    __syncthreads();
    if (tid == 0) asq[row] = red[0] + red[1] + red[2] + red[3];
}

// ---------------------------------------------------------------------------
// pack: Afrag[kwg 0..63][f 0..7][lane][8 bf16]
// ---------------------------------------------------------------------------
__global__ __launch_bounds__(64)
void pack_kernel(const float* __restrict__ concepts, const float* __restrict__ background,
                 const float* __restrict__ wcfc, unsigned short* __restrict__ Afrag) {
    const int f = blockIdx.x;
    const int kwg = blockIdx.y;
    const int l = threadIdx.x;
    const int row = 16 * f + (l & 15);
    const int kb = 32 * kwg + 8 * (l >> 4);
    const float* src = row_src(row, concepts, background, wcfc);
    unsigned o[4] = {0u, 0u, 0u, 0u};
    if (src) {
        const float4 f0 = *reinterpret_cast<const float4*>(src + kb);
        const float4 f1 = *reinterpret_cast<const float4*>(src + kb + 4);
        o[0] = cvtpk(f0.x, f0.y); o[1] = cvtpk(f0.z, f0.w);
        o[2] = cvtpk(f1.x, f1.y); o[3] = cvtpk(f1.z, f1.w);
    }
    *reinterpret_cast<uint4*>(Afrag + (((size_t)kwg * 8 + f) * 64 + l) * 8) =
        make_uint4(o[0], o[1], o[2], o[3]);
}

// ---------------------------------------------------------------------------
// fused_kernel, 512 thr (8 waves) — R16 structure with BK=64 (2 ksteps/iter):
//  blk < 128: whole-image GEMM dots[128][208] = A @ x_b. 32 iterations, each:
//    VM0+LBAR -> CONVERT both substeps -> LBAR -> DMA next pair -> 2x MFMA.
//    Halves barrier/iteration count vs R16 (tax-per-iteration hypothesis).
//  blk >= 128: pq body (w_lfc sweep), 32 wids per block.
// ---------------------------------------------------------------------------
__global__ __launch_bounds__(512)
void fused_kernel(const float* __restrict__ x,
                  const unsigned short* __restrict__ Afrag,
                  const float* __restrict__ asq_g,
                  float* __restrict__ out0,
                  float* __restrict__ lpart,
                  const float* __restrict__ wlfc,
                  const float* __restrict__ concepts,
                  const float* __restrict__ modulation,
                  float* __restrict__ Rm, float* __restrict__ Qs) {
    __shared__ __align__(16) char smem[SMEMSZ];
    const int tid = threadIdx.x;
    const int lane = tid & 63;
    const int w = tid >> 6;
    const int blkid = blockIdx.x;

    if (blkid < MAIN_BLKS) {
        const int b = blkid;
        unsigned short* XTu = (unsigned short*)(smem + XTBASE);

        const int lo = lane & 15, hi = lane >> 4;
        const char* xim = (const char*)x + (size_t)b * IMGB;
        const char* Ag = (const char*)Afrag;

        const bool act = tid < 416;
        const int h2 = (act && tid >= 208) ? 1 : 0;
        const int cc = act ? (tid - 208 * h2) : 0;

        f32x4 acc[13];
#pragma unroll
        for (int ct = 0; ct < 13; ++ct) acc[ct] = (f32x4){0.f, 0.f, 0.f, 0.f};
        float xs = 0.f;

#define ISSUE_X2(JJ) do {                                                       \
        _Pragma("unroll")                                                       \
        for (int s_ = 0; s_ < 2; ++s_) {                                        \
            const char* sx_ = xim + (size_t)(2 * (JJ) + s_) * XSTEP;            \
            char* xb_ = smem + s_ * XFSLOT;                                     \
            gl16(sx_ + (3 * w + 0) * 1024 + lane * 16, xb_ + (3 * w + 0) * 1024);\
            gl16(sx_ + (3 * w + 1) * 1024 + lane * 16, xb_ + (3 * w + 1) * 1024);\
            gl16(sx_ + (3 * w + 2) * 1024 + lane * 16, xb_ + (3 * w + 2) * 1024);\
            if (w == 0) gl16(sx_ + 24064 + lane * 16, xb_ + 24064);             \
        }                                                                       \
    } while (0)

#define ISSUE_A2(JJ) do {                                                       \
        _Pragma("unroll")                                                       \
        for (int s_ = 0; s_ < 2; ++s_)                                          \
            gl16(Ag + (size_t)(2 * (JJ) + s_) * 8192 + w * 1024 + lane * 16,    \
                 smem + ABASE + ((JJ) & 1) * 16384 + s_ * 8192 + w * 1024);     \
    } while (0)

#define VM0() do {                                                              \
        asm volatile("s_waitcnt vmcnt(0)" ::: "memory");                        \
        __builtin_amdgcn_sched_barrier(0);                                      \
    } while (0)

#define LBAR() do {                                                             \
        asm volatile("s_waitcnt lgkmcnt(0)" ::: "memory");                      \
        __builtin_amdgcn_s_barrier();                                           \
        __builtin_amdgcn_sched_barrier(0);                                      \
    } while (0)

#define CONVERT(S) do {                                                         \
        if (act) {                                                              \
            const float* xp_ = (const float*)(smem + (S) * XFSLOT)              \
                               + (16 * h2) * 196 + cc;                          \
            float v_[16];                                                       \
            _Pragma("unroll")                                                   \
            for (int q_ = 0; q_ < 16; ++q_) v_[q_] = xp_[q_ * 196];             \
            _Pragma("unroll")                                                   \
            for (int q_ = 0; q_ < 16; ++q_) xs += v_[q_] * v_[q_];              \
            unsigned u_[8];                                                     \
            _Pragma("unroll")                                                   \
            for (int p_ = 0; p_ < 8; ++p_)                                      \
                u_[p_] = cvtpk(v_[2 * p_], v_[2 * p_ + 1]);                     \
            unsigned short* xt_ = XTu + (S) * 8320 + cc * 40 + h2 * 16;         \
            *reinterpret_cast<uint4*>(xt_) = make_uint4(u_[0], u_[1], u_[2], u_[3]); \
            *reinterpret_cast<uint4*>(xt_ + 8) = make_uint4(u_[4], u_[5], u_[6], u_[7]); \
        }                                                                       \
    } while (0)

#define MFMA_STEP(S, JJ) do {                                                   \
        const char* Ab_ = smem + ABASE + ((JJ) & 1) * 16384 + (S) * 8192;       \
        const bf16x8 afr_ = *reinterpret_cast<const bf16x8*>(                   \
            Ab_ + ((w * 64 + lane) << 4));                                      \
        const char* xt_ = (const char*)XTu + (S) * 16640;                       \
        _Pragma("unroll")                                                       \
        for (int ct_ = 0; ct_ < 13; ++ct_) {                                    \
            const bf16x8 bfr_ = *reinterpret_cast<const bf16x8*>(               \
                xt_ + (ct_ * 16 + lo) * 80 + hi * 16);                          \
            acc[ct_] = __builtin_amdgcn_mfma_f32_16x16x32_bf16(                 \
                afr_, bfr_, acc[ct_], 0, 0, 0);                                 \
        }                                                                       \
    } while (0)

        ISSUE_X2(0); ISSUE_A2(0);
#pragma unroll 1
        for (int jj = 0; jj < 32; ++jj) {
            VM0(); LBAR();              // x pair + A pair landed; XT free
            CONVERT(0); CONVERT(1);     // Xf -> XT (both substeps)
            LBAR();                     // XT visible; Xf free
            if (jj < 31) ISSUE_X2(jj + 1);
            MFMA_STEP(0, jj);
            if (jj < 31) ISSUE_A2(jj + 1);
            MFMA_STEP(1, jj);
        }

        // ------------------ epilogue (R16, verbatim layout) ------------------
        float* pmw  = (float*)smem;             // [8][208] = 6656B
        float* xsqL = (float*)(smem + 6656);    // [2][208]
        float* xwL  = (float*)(smem + 8320);    // [208]

        __syncthreads();
        if (act) xsqL[h2 * 208 + cc] = xs;
        if (w == 7 && hi == 0) {
#pragma unroll
            for (int ct = 0; ct < 13; ++ct) xwL[ct * 16 + lo] = acc[ct][1]; // raw row 113
        }
        __syncthreads();

        float xq[13];
#pragma unroll
        for (int ct = 0; ct < 13; ++ct) {
            const int c = ct * 16 + lo;
            xq[ct] = xsqL[c] + xsqL[208 + c];
        }
        float aq[4];
#pragma unroll
        for (int rr = 0; rr < 4; ++rr) aq[rr] = asq_g[16 * w + 4 * hi + rr];
        const bool v4 = (w < 7);

        float mct[13];
#pragma unroll
        for (int ct = 0; ct < 13; ++ct) {
#pragma unroll
            for (int rr = 0; rr < 4; ++rr) {
                const float d2 = aq[rr] + xq[ct] - 2.f * acc[ct][rr];
                acc[ct][rr] = -sqrtf(fmaxf(d2, 0.f));
            }
            float mv = -3.4e38f;
            if (v4) mv = fmaxf(fmaxf(acc[ct][0], acc[ct][1]),
                               fmaxf(acc[ct][2], acc[ct][3]));
            else if (hi == 0) mv = acc[ct][0];          // row 112 only
            mv = fmaxf(mv, __shfl_xor(mv, 16));
            mv = fmaxf(mv, __shfl_xor(mv, 32));
            mct[ct] = mv;
        }
        if (hi == 0) {
#pragma unroll
            for (int ct = 0; ct < 13; ++ct) pmw[w * 208 + ct * 16 + lo] = mct[ct];
        }
        __syncthreads();
        float Mct[13];
#pragma unroll
        for (int ct = 0; ct < 13; ++ct) {
            float mm = -3.4e38f;
#pragma unroll
            for (int ww = 0; ww < 8; ++ww)
                mm = fmaxf(mm, pmw[ww * 208 + ct * 16 + lo]);
            Mct[ct] = mm;
        }
        __syncthreads();                 // all reads done before pmw reuse
        float sct[13];
#pragma unroll
        for (int ct = 0; ct < 13; ++ct) {
            float ss = 0.f;
#pragma unroll
            for (int rr = 0; rr < 4; ++rr) {
                const bool valid = v4 || (hi == 0 && rr == 0);
                const float e = valid ? __expf(acc[ct][rr] - Mct[ct]) : 0.f;
                acc[ct][rr] = e;
                ss += e;
            }
            ss += __shfl_xor(ss, 16);
            ss += __shfl_xor(ss, 32);
            sct[ct] = ss;
        }
        if (hi == 0) {
#pragma unroll
            for (int ct = 0; ct < 13; ++ct) pmw[w * 208 + ct * 16 + lo] = sct[ct];
        }
        __syncthreads();
        float inv[13];
#pragma unroll
        for (int ct = 0; ct < 13; ++ct) {
            float SS = 0.f;
#pragma unroll
            for (int ww = 0; ww < 8; ++ww) SS += pmw[ww * 208 + ct * 16 + lo];
            inv[ct] = 1.f / SS;
        }

        float* o0 = out0 + (size_t)b * KB * N;
#pragma unroll
        for (int ct = 0; ct < 13; ++ct) {
            const int c = ct * 16 + lo;
            const bool cv = c < N;
#pragma unroll
            for (int rr = 0; rr < 4; ++rr) {
                const int r = 16 * w + 4 * hi + rr;
                const bool valid = v4 || (hi == 0 && rr == 0);
                if (valid && cv) o0[(size_t)r * N + c] = acc[ct][rr] * inv[ct];
            }
        }
        if (v4) {
#pragma unroll
            for (int rr = 0; rr < 4; ++rr) {
                float pv = 0.f;
#pragma unroll
                for (int ct = 0; ct < 13; ++ct) {
                    const int c = ct * 16 + lo;
                    const float term = acc[ct][rr] * inv[ct] * xwL[c];
                    pv += (c < N) ? term : 0.f;
                }
                pv += __shfl_xor(pv, 1);
                pv += __shfl_xor(pv, 2);
                pv += __shfl_xor(pv, 4);
                pv += __shfl_xor(pv, 8);
                if (lo == 0) lpart[(size_t)b * K + 16 * w + 4 * hi + rr] = pv;
            }
        }
    } else {
        // ---------------- pq body: 32 wids per block (4 per wave) -----------
        const int wb = (blkid - MAIN_BLKS) * 32 + w * 4;
#pragma unroll
        for (int q = 0; q < 4; ++q) {
            const int wid = wb + q;
            const int o = wid / K;
            const int k = wid % K;
            const float4* wp = reinterpret_cast<const float4*>(wlfc + (size_t)o * CKC + (size_t)k * C);
            const float4* cp = reinterpret_cast<const float4*>(concepts + (size_t)k * C);
            const float4* mp = reinterpret_cast<const float4*>(modulation);
            float s1 = 0.f, s2 = 0.f;
#pragma unroll
            for (int it = 0; it < 8; ++it) {
                const int idx = it * 64 + lane;
                const float4 w4 = wp[idx];
                const float4 c4 = cp[idx];
                const float4 m4 = mp[idx];
                s1 += w4.x * c4.x + w4.y * c4.y + w4.z * c4.z + w4.w * c4.w;
                s2 += w4.x * m4.x + w4.y * m4.y + w4.z * m4.z + w4.w * m4.w;
            }
            for (int off = 32; off; off >>= 1) {
                s1 += __shfl_down(s1, off);
                s2 += __shfl_down(s2, off);
            }
            if (lane == 0) { Rm[wid] = s1 - s2; Qs[wid] = s2; }
        }
    }
}

// ---------------------------------------------------------------------------
__global__ __launch_bounds__(256)
void final_kernel(const float* __restrict__ lpart, const float* __restrict__ bcfc,
                  const float* __restrict__ Rm, const float* __restrict__ Qs,
                  const float* __restrict__ blfc,
                  float* __restrict__ out1, float* __restrict__ out2) {
    const int b = blockIdx.x;
    const int tid = threadIdx.x;
    __shared__ float g_s[K];
    if (tid < K) {
        const float v = lpart[(size_t)b * K + tid] + bcfc[0];
        const float g = 1.f / (1.f + __expf(-v));
        out1[b * K + tid] = g;
        g_s[tid] = g;
    }
    __syncthreads();
    if (tid < NCLS) {
        float acc = blfc[tid];
        const float* rp = Rm + (size_t)tid * K;
        const float* qp = Qs + (size_t)tid * K;
        for (int k = 0; k < K; ++k) acc = fmaf(g_s[k], rp[k], acc) + qp[k];
        out2[b * NCLS + tid] = acc;
    }
}

extern "C" void kernel_launch(void* const* d_in, const int* in_sizes, int n_in,
                              void* d_out, int out_size, void* d_ws, size_t ws_size,
                              hipStream_t stream) {
    const float* x          = (const float*)d_in[0];
    const float* concepts   = (const float*)d_in[1];
    const float* modulation = (const float*)d_in[2];
    const float* background = (const float*)d_in[3];
    const float* wcfc       = (const float*)d_in[4];
    const float* bcfc       = (const float*)d_in[5];
    const float* wlfc       = (const float*)d_in[6];
    const float* blfc       = (const float*)d_in[7];

    float* out  = (float*)d_out;
    float* out0 = out;
    float* out1 = out + OUT1_OFF;
    float* out2 = out + OUT2_OFF;

    float* ws    = (float*)d_ws;
    float* asq   = ws;                               // 128
    float* lpart = asq + MROWS;                      // B*K
    float* Rm    = lpart + (size_t)B * K;            // 22400
    float* Qs    = Rm + NCLS * K;                    // 22400
    unsigned short* Afrag = (unsigned short*)(Qs + NCLS * K);  // 512KB

    asq_kernel<<<MROWS, 256, 0, stream>>>(concepts, background, wcfc, asq);
    pack_kernel<<<dim3(8, 64), 64, 0, stream>>>(concepts, background, wcfc, Afrag);
    fused_kernel<<<MAIN_BLKS + PQ_BLKS, 512, 0, stream>>>(
        x, Afrag, asq, out0, lpart, wlfc, concepts, modulation, Rm, Qs);
    final_kernel<<<B, 256, 0, stream>>>(lpart, bcfc, Rm, Qs, blfc, out1, out2);
}